// Round 14
// baseline (567.782 us; speedup 1.0000x reference)
//
#include <hip/hip_runtime.h>

// GADBase diffusion: B=2, H=W=512, 128 iterations of fused diffuse+adjust.
// KS=8 temporal blocking, interior-only block ownership: 512 threads (8
// waves), 484 active own the interior 22x22 blocks of a 24x24-block (96x96)
// region around a 32x32 output tile; 4x4 block state lives in registers,
// per-step only block edges go through LDS (46KB single buffer, 2 barriers).
// Per-(tile,thread) L-folded coefficients precomputed once into d_ws (R13
// win). Step-0 neighbor edges via pre-loop LDS publish; only rim-adjacent
// threads touch global for step-0 rim edges.
// 16 diffuse + cvch + coefpack = 18 dispatches (T ~= 128*step + NDISP*fixed).
constexpr int Hh = 512, Ww = 512, Bn = 2;
constexpr int SWs = 128;
constexpr float Lf = 0.24f;
constexpr float Kf = 0.03f;
constexpr float EPSf = 1e-8f;
constexpr int NSTEPS = 128;

constexpr int NPIX = Bn * Hh * Ww;        // 524288
constexpr int CVN  = Bn * (Hh - 1) * Ww;  // 523264

constexpr int OT = 32;                    // output tile side
constexpr int KS = 8;                     // steps per launch (128 = 16*8)
constexpr int HALO = 4 * KS;              // 32
constexpr int G = (OT + 2 * HALO) / 4;    // 24x24 block grid (full region)
constexpr int GI = G - 2;                 // 22 interior blocks per side
constexpr int NB = GI * GI;               // 484 owned blocks
constexpr int NTHR = 512;                 // 8 waves
constexpr int REC = 20;                   // edge record stride (dwords)
constexpr int NWG = Bn * (Hh / OT) * (Ww / OT);  // 512
constexpr int NLAUNCH = NSTEPS / KS;      // 16
constexpr int CREC = 40;                  // coef record dwords per thread

__device__ __forceinline__ int clampi(int v, int lo, int hi) {
  return min(max(v, lo), hi);
}
// Linear record offset; REC=20 staggers bank bases. Records use 16 of 20
// dwords; NO per-record shift (round-7 lesson: shifts >=4 dwords collide).
__device__ __forceinline__ int recof(int t) { return t * REC; }

// ---------------------------------------------------------------------------
// Kernel 1: edge-stopping coefficients cv, ch (once, into d_out slots).
// ---------------------------------------------------------------------------
__global__ __launch_bounds__(256) void cvch_kernel(
    const float* __restrict__ img, const float* __restrict__ guide,
    float* __restrict__ cv, float* __restrict__ ch) {
  int idx = blockIdx.x * blockDim.x + threadIdx.x;
  if (idx >= NPIX) return;
  int x = idx & (Ww - 1);
  int y = (idx >> 9) & (Hh - 1);
  int b = idx >> 18;
  const float inv_k2 = 1.0f / (Kf * Kf);
  const float* f0 = img + (size_t)b * Hh * Ww;
  const float* g0 = guide + (size_t)b * 3 * Hh * Ww;
  const float* g1 = g0 + Hh * Ww;
  const float* g2 = g1 + Hh * Ww;
  int p = y * Ww + x;
  float c0 = f0[p], c1 = g0[p], c2 = g1[p], c3 = g2[p];
  if (y < Hh - 1) {
    int q = p + Ww;
    float m = (fabsf(f0[q] - c0) + fabsf(g0[q] - c1) +
               fabsf(g1[q] - c2) + fabsf(g2[q] - c3)) * 0.25f;
    cv[(b * (Hh - 1) + y) * Ww + x] = 1.0f / (1.0f + m * m * inv_k2);
  }
  if (x < Ww - 1) {
    int q = p + 1;
    float m = (fabsf(f0[q] - c0) + fabsf(g0[q] - c1) +
               fabsf(g1[q] - c2) + fabsf(g2[q] - c3)) * 0.25f;
    ch[(b * Hh + y) * (Ww - 1) + x] = 1.0f / (1.0f + m * m * inv_k2);
  }
}

// ---------------------------------------------------------------------------
// Kernel 1b: pack per-(tile,thread) L-folded coefficients into d_ws records.
// Record (CREC=40 dwords): cvk[5][4] at +0..19, chk[4][5] at +20..39.
// Thread mapping EXACTLY matches diffuse8_kernel (interior 22x22 of 24x24).
// ---------------------------------------------------------------------------
__global__ __launch_bounds__(NTHR) void coefpack_kernel(
    const float* __restrict__ cv, const float* __restrict__ ch,
    float* __restrict__ crec) {
  int wg = blockIdx.x;
  int b  = wg >> 8;
  int t  = wg & 255;
  int Ty0 = (t >> 4) * OT;
  int Tx0 = (t & 15) * OT;
  int tid = threadIdx.x;
  if (tid >= NB) return;                   // idle slots left as-is
  int iy = tid / GI, ix = tid - iy * GI;
  int by = 1 + iy, bx = 1 + ix;
  int gy0 = Ty0 - HALO + 4 * by;
  int gx0 = Tx0 - HALO + 4 * bx;

  const float* cvb = cv + (size_t)b * (Hh - 1) * Ww;
  const float* chb = ch + (size_t)b * Hh * (Ww - 1);
  float* r = crec + ((size_t)wg * NTHR + tid) * CREC;

#pragma unroll
  for (int k = 0; k < 5; ++k) {
    int ro = gy0 - 1 + k;
    float4 o;
    if (ro < 0 || ro > Hh - 2) {
      o = make_float4(0.f, 0.f, 0.f, 0.f);
    } else if (gx0 < 0) {
      float v = Lf * cvb[ro * Ww];
      o = make_float4(v, v, v, v);
    } else if (gx0 > Ww - 4) {
      float v = Lf * cvb[ro * Ww + Ww - 1];
      o = make_float4(v, v, v, v);
    } else {
      float4 t4 = *reinterpret_cast<const float4*>(&cvb[ro * Ww + gx0]);
      o = make_float4(Lf * t4.x, Lf * t4.y, Lf * t4.z, Lf * t4.w);
    }
    *reinterpret_cast<float4*>(r + 4 * k) = o;
  }
#pragma unroll
  for (int rr = 0; rr < 4; ++rr) {
    int ri = clampi(gy0 + rr, 0, Hh - 1);
#pragma unroll
    for (int j = 0; j < 5; ++j) {
      int e = gx0 - 1 + j;
      r[20 + rr * 5 + j] =
          (e >= 0 && e <= Ww - 2) ? Lf * chb[ri * (Ww - 1) + e] : 0.0f;
    }
  }
}

// ---------------------------------------------------------------------------
// Kernel 2: 8 diffusion+adjust steps per launch, block state in registers.
// Validity induction: V_t = [t, 24-t)^2 block set holds true time-t values;
// publish gate after step s is [s+1, 23-s)^2 which exactly covers step-s+1
// readers; V_8 = [8,16)^2 = the 32x32 output tile. Rim blocks are unowned:
// rim-adjacent threads load their rim-side step-0 edge from global; all
// other step-0 edges come from a pre-loop LDS publish of own-block edges.
// Off-image pixels are decoupled (boundary-crossing coefficients exactly 0);
// garbage (idle-lane / rim-record) values are never consumed by valid blocks.
// ---------------------------------------------------------------------------
__global__ __launch_bounds__(NTHR, 4) void diffuse8_kernel(
    const float* __restrict__ src, float* __restrict__ dst,
    const float* __restrict__ crec,
    const float* __restrict__ source, const float* __restrict__ mask) {
  __shared__ __align__(16) float ebuf[G * G * REC];  // 46.1 KB

  int wg = blockIdx.x;
  int b  = wg >> 8;                        // 256 tiles per image
  int t  = wg & 255;
  int Ty0 = (t >> 4) * OT;
  int Tx0 = (t & 15) * OT;

  int tid = threadIdx.x;
  bool act = tid < NB;
  int tt = min(tid, NB - 1);               // idle threads alias last block
  int iy = tt / GI, ix = tt - iy * GI;     // const divisor -> magic mul
  int by = 1 + iy, bx = 1 + ix;            // block coords in 24x24 grid
  int gy0 = Ty0 - HALO + 4 * by;           // block origin (may be off-image)
  int gx0 = Tx0 - HALO + 4 * bx;

  int blk = by * G + bx;
  int oMy = recof(blk);
  int oU  = recof(blk - G) + 4;            // upper neighbor's bottom row
  int oD  = recof(blk + G) + 0;            // lower neighbor's top row
  int oL  = recof(blk - 1) + 12;           // left neighbor's right col
  int oR  = recof(blk + 1) + 8;            // right neighbor's left col

  const size_t ib = (size_t)b * Hh * Ww;
  const float* S = src + ib;
  float* D = dst + ib;

  auto ld4 = [&](int gy, int gx) -> float4 {
    gy = clampi(gy, 0, Hh - 1);
    if (gx < 0)      { float v = S[gy * Ww];          return make_float4(v, v, v, v); }
    if (gx > Ww - 4) { float v = S[gy * Ww + Ww - 1]; return make_float4(v, v, v, v); }
    return *reinterpret_cast<const float4*>(&S[gy * Ww + gx]);
  };

  // --- streaming coefficient load (precomputed, L folded, borders zeroed) -
  float cvk[5][4];
  float chk[4][5];
  {
    const float* r = crec + ((size_t)wg * NTHR + tid) * CREC;
#pragma unroll
    for (int k = 0; k < 5; ++k) {
      float4 t4 = *reinterpret_cast<const float4*>(r + 4 * k);
      cvk[k][0] = t4.x; cvk[k][1] = t4.y; cvk[k][2] = t4.z; cvk[k][3] = t4.w;
    }
#pragma unroll
    for (int rr = 0; rr < 4; ++rr)
#pragma unroll
      for (int j = 0; j < 5; ++j) chk[rr][j] = r[20 + rr * 5 + j];
  }

  // --- own 4x4 block (time 0) ---------------------------------------------
  float I[4][4];
#pragma unroll
  for (int r = 0; r < 4; ++r) {
    float4 t4 = ld4(gy0 + r, gx0);
    I[r][0] = t4.x; I[r][1] = t4.y; I[r][2] = t4.z; I[r][3] = t4.w;
  }

  int sy = clampi(gy0 >> 2, 0, SWs - 1);
  int sx = clampi(gx0 >> 2, 0, SWs - 1);
  int sidx = (b * SWs + sy) * SWs + sx;
  float srcv = source[sidx];
  bool mskv = mask[sidx] > 0.5f;

  // --- pre-loop publish of time-0 edges (replaces 10 global loads/thread) -
  if (act) {
    *reinterpret_cast<float4*>(ebuf + oMy + 0) =
        make_float4(I[0][0], I[0][1], I[0][2], I[0][3]);
    *reinterpret_cast<float4*>(ebuf + oMy + 4) =
        make_float4(I[3][0], I[3][1], I[3][2], I[3][3]);
    *reinterpret_cast<float4*>(ebuf + oMy + 8) =
        make_float4(I[0][0], I[1][0], I[2][0], I[3][0]);
    *reinterpret_cast<float4*>(ebuf + oMy + 12) =
        make_float4(I[0][3], I[1][3], I[2][3], I[3][3]);
  }
  __syncthreads();

  float nT[4], nB[4], nL[4], nR[4];

#pragma unroll
  for (int s = 0; s < KS; ++s) {
    // --- read neighbor edges (LDS; step-0 rim sides from global) ---------
    {
      float4 t4;
      if (s == 0 && by == 1) t4 = ld4(gy0 - 1, gx0);
      else t4 = *reinterpret_cast<const float4*>(ebuf + oU);
      nT[0] = t4.x; nT[1] = t4.y; nT[2] = t4.z; nT[3] = t4.w;
      if (s == 0 && by == GI) t4 = ld4(gy0 + 4, gx0);
      else t4 = *reinterpret_cast<const float4*>(ebuf + oD);
      nB[0] = t4.x; nB[1] = t4.y; nB[2] = t4.z; nB[3] = t4.w;
      if (s == 0 && bx == 1) {
        int cL = clampi(gx0 - 1, 0, Ww - 1);
#pragma unroll
        for (int r = 0; r < 4; ++r)
          nL[r] = S[clampi(gy0 + r, 0, Hh - 1) * Ww + cL];
      } else {
        t4 = *reinterpret_cast<const float4*>(ebuf + oL);
        nL[0] = t4.x; nL[1] = t4.y; nL[2] = t4.z; nL[3] = t4.w;
      }
      if (s == 0 && bx == GI) {
        int cR = clampi(gx0 + 4, 0, Ww - 1);
#pragma unroll
        for (int r = 0; r < 4; ++r)
          nR[r] = S[clampi(gy0 + r, 0, Hh - 1) * Ww + cR];
      } else {
        t4 = *reinterpret_cast<const float4*>(ebuf + oR);
        nR[0] = t4.x; nR[1] = t4.y; nR[2] = t4.z; nR[3] = t4.w;
      }
    }

    // --- in-place stencil with row/col original-value delay buffers ------
    float sum = 0.0f;
    float rowOrig[4];
#pragma unroll
    for (int r = 0; r < 4; ++r) {
      float leftOrig = 0.0f;
#pragma unroll
      for (int c = 0; c < 4; ++c) {
        float cc = I[r][c];
        float up = (r == 0) ? nT[c] : rowOrig[c];
        float dn = (r == 3) ? nB[c] : I[r + 1][c];
        float lf = (c == 0) ? nL[r] : leftOrig;
        float rt = (c == 3) ? nR[r] : I[r][c + 1];
        float acc = cc + cvk[r + 1][c] * (dn - cc) - cvk[r][c] * (cc - up)
                       + chk[r][c + 1] * (rt - cc) - chk[r][c] * (cc - lf);
        rowOrig[c] = cc;
        leftOrig = cc;
        I[r][c] = acc;
        sum += acc;
      }
    }
    float ratio = mskv ? 1.0f : __fdividef(srcv, sum * 0.0625f + EPSf);
#pragma unroll
    for (int r = 0; r < 4; ++r)
#pragma unroll
      for (int c = 0; c < 4; ++c) I[r][c] *= ratio;

    if (s == KS - 1) {
      // central 8x8 blocks [KS, G-KS)^2 == the 32x32 output tile
      if (by >= KS && by < G - KS && bx >= KS && bx < G - KS) {
#pragma unroll
        for (int r = 0; r < 4; ++r)
          *reinterpret_cast<float4*>(&D[(gy0 + r) * Ww + gx0]) =
              make_float4(I[r][0], I[r][1], I[r][2], I[r][3]);
      }
    } else {
      __syncthreads();                     // WAR: reads(s) before overwrite
      if (act && by > s && by < G - 1 - s && bx > s && bx < G - 1 - s) {
        *reinterpret_cast<float4*>(ebuf + oMy + 0) =
            make_float4(I[0][0], I[0][1], I[0][2], I[0][3]);   // top row
        *reinterpret_cast<float4*>(ebuf + oMy + 4) =
            make_float4(I[3][0], I[3][1], I[3][2], I[3][3]);   // bottom row
        *reinterpret_cast<float4*>(ebuf + oMy + 8) =
            make_float4(I[0][0], I[1][0], I[2][0], I[3][0]);   // left col
        *reinterpret_cast<float4*>(ebuf + oMy + 12) =
            make_float4(I[0][3], I[1][3], I[2][3], I[3][3]);   // right col
      }
      __syncthreads();                     // publish(s) before reads(s+1)
    }
  }
}

// ---------------------------------------------------------------------------
// Fallback (small ws): one launch per step.
// ---------------------------------------------------------------------------
constexpr int FT = 32;
__global__ __launch_bounds__(64) void step_kernel(
    const float* __restrict__ src, float* __restrict__ dst,
    const float* __restrict__ cv, const float* __restrict__ ch,
    const float* __restrict__ source, const float* __restrict__ mask) {
  __shared__ float sIl[FT + 2][FT + 3];
  int b = blockIdx.z;
  int ty0 = blockIdx.y * FT, tx0 = blockIdx.x * FT;
  const float* I = src + (size_t)b * Hh * Ww;
  int tid = threadIdx.x;
  for (int i = tid; i < (FT + 2) * (FT + 2); i += 64) {
    int ly = i / (FT + 2), lx = i % (FT + 2);
    int gy = max(0, min(Hh - 1, ty0 + ly - 1));
    int gx = max(0, min(Ww - 1, tx0 + lx - 1));
    sIl[ly][lx] = I[gy * Ww + gx];
  }
  __syncthreads();
  int bby = tid >> 3, bbx = tid & 7;
  int py0 = bby * 4, px0 = bbx * 4;
  int gy0 = ty0 + py0, gx0 = tx0 + px0;
  const float* cvb = cv + (size_t)b * (Hh - 1) * Ww;
  const float* chb = ch + (size_t)b * Hh * (Ww - 1);
  float v[4][4]; float sum = 0.0f;
#pragma unroll
  for (int dy = 0; dy < 4; ++dy) {
    int y = gy0 + dy, ly = py0 + dy + 1;
#pragma unroll
    for (int dx = 0; dx < 4; ++dx) {
      int x = gx0 + dx, lx = px0 + dx + 1;
      float cc = sIl[ly][lx];
      float acc = cc;
      if (y < Hh - 1) acc += Lf * cvb[y * Ww + x] * (sIl[ly + 1][lx] - cc);
      if (y > 0)      acc -= Lf * cvb[(y - 1) * Ww + x] * (cc - sIl[ly - 1][lx]);
      if (x < Ww - 1) acc += Lf * chb[y * (Ww - 1) + x] * (sIl[ly][lx + 1] - cc);
      if (x > 0)      acc -= Lf * chb[y * (Ww - 1) + x - 1] * (cc - sIl[ly][lx - 1]);
      v[dy][dx] = acc; sum += acc;
    }
  }
  int sidx = (b * SWs + (gy0 >> 2)) * SWs + (gx0 >> 2);
  float ratio = (mask[sidx] > 0.5f) ? 1.0f : source[sidx] / (sum * 0.0625f + EPSf);
  float* D = dst + (size_t)b * Hh * Ww;
#pragma unroll
  for (int dy = 0; dy < 4; ++dy)
    *reinterpret_cast<float4*>(&D[(gy0 + dy) * Ww + gx0]) =
        make_float4(v[dy][0] * ratio, v[dy][1] * ratio,
                    v[dy][2] * ratio, v[dy][3] * ratio);
}

// ---------------------------------------------------------------------------
extern "C" void kernel_launch(void* const* d_in, const int* in_sizes, int n_in,
                              void* d_out, int out_size, void* d_ws, size_t ws_size,
                              hipStream_t stream) {
  const float* guide  = (const float*)d_in[0];
  const float* ybic   = (const float*)d_in[1];
  const float* source = (const float*)d_in[2];
  const float* mask   = (const float*)d_in[3];

  float* out   = (float*)d_out;
  float* ypred = out;                 // 524288
  float* cv    = out + NPIX;          // 523264
  float* ch    = out + NPIX + CVN;    // 523264

  cvch_kernel<<<dim3((NPIX + 255) / 256), dim3(256), 0, stream>>>(ybic, guide, cv, ch);

  size_t needPing = (size_t)2 * NPIX * sizeof(float);                 // 4 MB
  size_t needCoef = (size_t)NWG * NTHR * CREC * sizeof(float);        // 42 MB

  if (ws_size >= needPing + needCoef) {
    float* wsb0 = (float*)d_ws;
    float* wsb1 = wsb0 + NPIX;
    float* crec = wsb1 + NPIX;
    coefpack_kernel<<<dim3(NWG), dim3(NTHR), 0, stream>>>(cv, ch, crec);
    const float* sp = ybic;
    for (int l = 0; l < NLAUNCH; ++l) {
      float* dp = (l == NLAUNCH - 1) ? ypred : ((l & 1) ? wsb1 : wsb0);
      diffuse8_kernel<<<dim3(NWG), dim3(NTHR), 0, stream>>>(sp, dp, crec,
                                                            source, mask);
      sp = dp;
    }
  } else {
    float* wsbuf = (float*)d_ws;
    dim3 grid(Ww / FT, Hh / FT, Bn);
    const float* sp = ybic;
    for (int it = 0; it < NSTEPS; ++it) {
      float* dp = (it & 1) ? ypred : wsbuf;
      step_kernel<<<grid, dim3(64), 0, stream>>>(sp, dp, cv, ch, source, mask);
      sp = dp;
    }
  }
}

// Round 15
// 330.980 us; speedup vs baseline: 1.7155x; 1.7155x over previous
//
#include <hip/hip_runtime.h>
#include <hip/hip_fp16.h>

// GADBase diffusion: B=2, H=W=512, 128 iterations of fused diffuse+adjust.
// KS=8 temporal blocking (R14 geometry, correctness-proven) + f16-packed
// coefficient records (20 dwords/thread -> 21 MB total = 2.6 MB/XCD, fits
// per-XCD L2; R14's 42 MB f32 records overflowed L2 -> 268 MB HBM write
// amplification + 14us/launch HBM re-reads). f16 unpacked ONCE in prologue
// to the proven f32 inner loop (R10's mistake was per-step unpack).
// 16 diffuse + cvch + coefpack = 18 dispatches.
constexpr int Hh = 512, Ww = 512, Bn = 2;
constexpr int SWs = 128;
constexpr float Lf = 0.24f;
constexpr float Kf = 0.03f;
constexpr float EPSf = 1e-8f;
constexpr int NSTEPS = 128;

constexpr int NPIX = Bn * Hh * Ww;        // 524288
constexpr int CVN  = Bn * (Hh - 1) * Ww;  // 523264

constexpr int OT = 32;                    // output tile side
constexpr int KS = 8;                     // steps per launch (128 = 16*8)
constexpr int HALO = 4 * KS;              // 32
constexpr int G = (OT + 2 * HALO) / 4;    // 24x24 block grid (full region)
constexpr int GI = G - 2;                 // 22 interior blocks per side
constexpr int NB = GI * GI;               // 484 owned blocks
constexpr int NTHR = 512;                 // 8 waves
constexpr int REC = 20;                   // edge record stride (dwords)
constexpr int NWG = Bn * (Hh / OT) * (Ww / OT);  // 512
constexpr int NLAUNCH = NSTEPS / KS;      // 16
constexpr int CREC = 20;                  // coef record dwords (40 f16)

__device__ __forceinline__ int clampi(int v, int lo, int hi) {
  return min(max(v, lo), hi);
}
__device__ __forceinline__ int recof(int t) { return t * REC; }

__device__ __forceinline__ unsigned packh2(float a, float b) {
  __half2 h = __floats2half2_rn(a, b);
  return reinterpret_cast<unsigned&>(h);
}
__device__ __forceinline__ float2 unpackh2(unsigned v) {
  __half2 h = reinterpret_cast<__half2&>(v);
  return __half22float2(h);
}

// ---------------------------------------------------------------------------
// Kernel 1: edge-stopping coefficients cv, ch (once, into d_out slots).
// ---------------------------------------------------------------------------
__global__ __launch_bounds__(256) void cvch_kernel(
    const float* __restrict__ img, const float* __restrict__ guide,
    float* __restrict__ cv, float* __restrict__ ch) {
  int idx = blockIdx.x * blockDim.x + threadIdx.x;
  if (idx >= NPIX) return;
  int x = idx & (Ww - 1);
  int y = (idx >> 9) & (Hh - 1);
  int b = idx >> 18;
  const float inv_k2 = 1.0f / (Kf * Kf);
  const float* f0 = img + (size_t)b * Hh * Ww;
  const float* g0 = guide + (size_t)b * 3 * Hh * Ww;
  const float* g1 = g0 + Hh * Ww;
  const float* g2 = g1 + Hh * Ww;
  int p = y * Ww + x;
  float c0 = f0[p], c1 = g0[p], c2 = g1[p], c3 = g2[p];
  if (y < Hh - 1) {
    int q = p + Ww;
    float m = (fabsf(f0[q] - c0) + fabsf(g0[q] - c1) +
               fabsf(g1[q] - c2) + fabsf(g2[q] - c3)) * 0.25f;
    cv[(b * (Hh - 1) + y) * Ww + x] = 1.0f / (1.0f + m * m * inv_k2);
  }
  if (x < Ww - 1) {
    int q = p + 1;
    float m = (fabsf(f0[q] - c0) + fabsf(g0[q] - c1) +
               fabsf(g1[q] - c2) + fabsf(g2[q] - c3)) * 0.25f;
    ch[(b * Hh + y) * (Ww - 1) + x] = 1.0f / (1.0f + m * m * inv_k2);
  }
}

// ---------------------------------------------------------------------------
// Kernel 1b: pack per-(tile,thread) L-folded coefficients as f16 pairs.
// Record (20 dwords = 40 halfs): h[0..19] = cvk[5][4] k-major,
// h[20..39] = chk[4][5] r-major. Thread mapping matches diffuse8_kernel.
// 80B/thread contiguous -> dense wave stores, no write amplification.
// ---------------------------------------------------------------------------
__global__ __launch_bounds__(NTHR) void coefpack_kernel(
    const float* __restrict__ cv, const float* __restrict__ ch,
    unsigned* __restrict__ crec) {
  int wg = blockIdx.x;
  int b  = wg >> 8;
  int t  = wg & 255;
  int Ty0 = (t >> 4) * OT;
  int Tx0 = (t & 15) * OT;
  int tid = threadIdx.x;
  if (tid >= NB) return;
  int iy = tid / GI, ix = tid - iy * GI;
  int by = 1 + iy, bx = 1 + ix;
  int gy0 = Ty0 - HALO + 4 * by;
  int gx0 = Tx0 - HALO + 4 * bx;

  const float* cvb = cv + (size_t)b * (Hh - 1) * Ww;
  const float* chb = ch + (size_t)b * Hh * (Ww - 1);

  float ck[5][4];
#pragma unroll
  for (int k = 0; k < 5; ++k) {
    int ro = gy0 - 1 + k;
    if (ro < 0 || ro > Hh - 2) {
      ck[k][0] = ck[k][1] = ck[k][2] = ck[k][3] = 0.0f;
    } else if (gx0 < 0) {
      float v = Lf * cvb[ro * Ww];
      ck[k][0] = ck[k][1] = ck[k][2] = ck[k][3] = v;
    } else if (gx0 > Ww - 4) {
      float v = Lf * cvb[ro * Ww + Ww - 1];
      ck[k][0] = ck[k][1] = ck[k][2] = ck[k][3] = v;
    } else {
      float4 t4 = *reinterpret_cast<const float4*>(&cvb[ro * Ww + gx0]);
      ck[k][0] = Lf * t4.x; ck[k][1] = Lf * t4.y;
      ck[k][2] = Lf * t4.z; ck[k][3] = Lf * t4.w;
    }
  }
  float cj[20];
#pragma unroll
  for (int rr = 0; rr < 4; ++rr) {
    int ri = clampi(gy0 + rr, 0, Hh - 1);
#pragma unroll
    for (int j = 0; j < 5; ++j) {
      int e = gx0 - 1 + j;
      cj[rr * 5 + j] =
          (e >= 0 && e <= Ww - 2) ? Lf * chb[ri * (Ww - 1) + e] : 0.0f;
    }
  }

  unsigned u[20];
#pragma unroll
  for (int k = 0; k < 5; ++k) {
    u[k * 2 + 0] = packh2(ck[k][0], ck[k][1]);
    u[k * 2 + 1] = packh2(ck[k][2], ck[k][3]);
  }
#pragma unroll
  for (int m = 0; m < 10; ++m)
    u[10 + m] = packh2(cj[2 * m], cj[2 * m + 1]);

  unsigned* r = crec + ((size_t)wg * NTHR + tid) * CREC;
#pragma unroll
  for (int q = 0; q < 5; ++q)
    *reinterpret_cast<uint4*>(r + 4 * q) =
        make_uint4(u[4 * q], u[4 * q + 1], u[4 * q + 2], u[4 * q + 3]);
}

// ---------------------------------------------------------------------------
// Kernel 2: 8 diffusion+adjust steps per launch, block state in registers.
// Identical to R14's verified kernel except the coefficient prologue:
// 5 uint4 loads + one-time f16->f32 unpack into the same cvk/chk arrays.
// Validity induction unchanged: V_t = [t, 24-t)^2; publish gate after step s
// is [s+1, 23-s)^2; V_8 = [8,16)^2 = the 32x32 output tile.
// ---------------------------------------------------------------------------
__global__ __launch_bounds__(NTHR, 4) void diffuse8_kernel(
    const float* __restrict__ src, float* __restrict__ dst,
    const unsigned* __restrict__ crec,
    const float* __restrict__ source, const float* __restrict__ mask) {
  __shared__ __align__(16) float ebuf[G * G * REC];  // 46.1 KB

  int wg = blockIdx.x;
  int b  = wg >> 8;                        // 256 tiles per image
  int t  = wg & 255;
  int Ty0 = (t >> 4) * OT;
  int Tx0 = (t & 15) * OT;

  int tid = threadIdx.x;
  bool act = tid < NB;
  int tt = min(tid, NB - 1);               // idle threads alias last block
  int iy = tt / GI, ix = tt - iy * GI;     // const divisor -> magic mul
  int by = 1 + iy, bx = 1 + ix;            // block coords in 24x24 grid
  int gy0 = Ty0 - HALO + 4 * by;           // block origin (may be off-image)
  int gx0 = Tx0 - HALO + 4 * bx;

  int blk = by * G + bx;
  int oMy = recof(blk);
  int oU  = recof(blk - G) + 4;            // upper neighbor's bottom row
  int oD  = recof(blk + G) + 0;            // lower neighbor's top row
  int oL  = recof(blk - 1) + 12;           // left neighbor's right col
  int oR  = recof(blk + 1) + 8;            // right neighbor's left col

  const size_t ib = (size_t)b * Hh * Ww;
  const float* S = src + ib;
  float* D = dst + ib;

  auto ld4 = [&](int gy, int gx) -> float4 {
    gy = clampi(gy, 0, Hh - 1);
    if (gx < 0)      { float v = S[gy * Ww];          return make_float4(v, v, v, v); }
    if (gx > Ww - 4) { float v = S[gy * Ww + Ww - 1]; return make_float4(v, v, v, v); }
    return *reinterpret_cast<const float4*>(&S[gy * Ww + gx]);
  };

  // --- coefficient load: 5 uint4 (L2-resident) + one-time f16 unpack -----
  float cvk[5][4];
  float chk[4][5];
  {
    const unsigned* r = crec + ((size_t)wg * NTHR + tid) * CREC;
    unsigned w[20];
#pragma unroll
    for (int q = 0; q < 5; ++q) {
      uint4 u4 = *reinterpret_cast<const uint4*>(r + 4 * q);
      w[4 * q] = u4.x; w[4 * q + 1] = u4.y;
      w[4 * q + 2] = u4.z; w[4 * q + 3] = u4.w;
    }
    float cf[40];
#pragma unroll
    for (int i = 0; i < 20; ++i) {
      float2 f = unpackh2(w[i]);
      cf[2 * i] = f.x; cf[2 * i + 1] = f.y;
    }
#pragma unroll
    for (int k = 0; k < 5; ++k)
#pragma unroll
      for (int c = 0; c < 4; ++c) cvk[k][c] = cf[k * 4 + c];
#pragma unroll
    for (int rr = 0; rr < 4; ++rr)
#pragma unroll
      for (int j = 0; j < 5; ++j) chk[rr][j] = cf[20 + rr * 5 + j];
  }

  // --- own 4x4 block (time 0) ---------------------------------------------
  float I[4][4];
#pragma unroll
  for (int r = 0; r < 4; ++r) {
    float4 t4 = ld4(gy0 + r, gx0);
    I[r][0] = t4.x; I[r][1] = t4.y; I[r][2] = t4.z; I[r][3] = t4.w;
  }

  int sy = clampi(gy0 >> 2, 0, SWs - 1);
  int sx = clampi(gx0 >> 2, 0, SWs - 1);
  int sidx = (b * SWs + sy) * SWs + sx;
  float srcv = source[sidx];
  bool mskv = mask[sidx] > 0.5f;

  // --- pre-loop publish of time-0 edges -----------------------------------
  if (act) {
    *reinterpret_cast<float4*>(ebuf + oMy + 0) =
        make_float4(I[0][0], I[0][1], I[0][2], I[0][3]);
    *reinterpret_cast<float4*>(ebuf + oMy + 4) =
        make_float4(I[3][0], I[3][1], I[3][2], I[3][3]);
    *reinterpret_cast<float4*>(ebuf + oMy + 8) =
        make_float4(I[0][0], I[1][0], I[2][0], I[3][0]);
    *reinterpret_cast<float4*>(ebuf + oMy + 12) =
        make_float4(I[0][3], I[1][3], I[2][3], I[3][3]);
  }
  __syncthreads();

  float nT[4], nB[4], nL[4], nR[4];

#pragma unroll
  for (int s = 0; s < KS; ++s) {
    // --- read neighbor edges (LDS; step-0 rim sides from global) ---------
    {
      float4 t4;
      if (s == 0 && by == 1) t4 = ld4(gy0 - 1, gx0);
      else t4 = *reinterpret_cast<const float4*>(ebuf + oU);
      nT[0] = t4.x; nT[1] = t4.y; nT[2] = t4.z; nT[3] = t4.w;
      if (s == 0 && by == GI) t4 = ld4(gy0 + 4, gx0);
      else t4 = *reinterpret_cast<const float4*>(ebuf + oD);
      nB[0] = t4.x; nB[1] = t4.y; nB[2] = t4.z; nB[3] = t4.w;
      if (s == 0 && bx == 1) {
        int cL = clampi(gx0 - 1, 0, Ww - 1);
#pragma unroll
        for (int r = 0; r < 4; ++r)
          nL[r] = S[clampi(gy0 + r, 0, Hh - 1) * Ww + cL];
      } else {
        t4 = *reinterpret_cast<const float4*>(ebuf + oL);
        nL[0] = t4.x; nL[1] = t4.y; nL[2] = t4.z; nL[3] = t4.w;
      }
      if (s == 0 && bx == GI) {
        int cR = clampi(gx0 + 4, 0, Ww - 1);
#pragma unroll
        for (int r = 0; r < 4; ++r)
          nR[r] = S[clampi(gy0 + r, 0, Hh - 1) * Ww + cR];
      } else {
        t4 = *reinterpret_cast<const float4*>(ebuf + oR);
        nR[0] = t4.x; nR[1] = t4.y; nR[2] = t4.z; nR[3] = t4.w;
      }
    }

    // --- in-place stencil with row/col original-value delay buffers ------
    float sum = 0.0f;
    float rowOrig[4];
#pragma unroll
    for (int r = 0; r < 4; ++r) {
      float leftOrig = 0.0f;
#pragma unroll
      for (int c = 0; c < 4; ++c) {
        float cc = I[r][c];
        float up = (r == 0) ? nT[c] : rowOrig[c];
        float dn = (r == 3) ? nB[c] : I[r + 1][c];
        float lf = (c == 0) ? nL[r] : leftOrig;
        float rt = (c == 3) ? nR[r] : I[r][c + 1];
        float acc = cc + cvk[r + 1][c] * (dn - cc) - cvk[r][c] * (cc - up)
                       + chk[r][c + 1] * (rt - cc) - chk[r][c] * (cc - lf);
        rowOrig[c] = cc;
        leftOrig = cc;
        I[r][c] = acc;
        sum += acc;
      }
    }
    float ratio = mskv ? 1.0f : __fdividef(srcv, sum * 0.0625f + EPSf);
#pragma unroll
    for (int r = 0; r < 4; ++r)
#pragma unroll
      for (int c = 0; c < 4; ++c) I[r][c] *= ratio;

    if (s == KS - 1) {
      // central 8x8 blocks [KS, G-KS)^2 == the 32x32 output tile
      if (by >= KS && by < G - KS && bx >= KS && bx < G - KS) {
#pragma unroll
        for (int r = 0; r < 4; ++r)
          *reinterpret_cast<float4*>(&D[(gy0 + r) * Ww + gx0]) =
              make_float4(I[r][0], I[r][1], I[r][2], I[r][3]);
      }
    } else {
      __syncthreads();                     // WAR: reads(s) before overwrite
      if (act && by > s && by < G - 1 - s && bx > s && bx < G - 1 - s) {
        *reinterpret_cast<float4*>(ebuf + oMy + 0) =
            make_float4(I[0][0], I[0][1], I[0][2], I[0][3]);   // top row
        *reinterpret_cast<float4*>(ebuf + oMy + 4) =
            make_float4(I[3][0], I[3][1], I[3][2], I[3][3]);   // bottom row
        *reinterpret_cast<float4*>(ebuf + oMy + 8) =
            make_float4(I[0][0], I[1][0], I[2][0], I[3][0]);   // left col
        *reinterpret_cast<float4*>(ebuf + oMy + 12) =
            make_float4(I[0][3], I[1][3], I[2][3], I[3][3]);   // right col
      }
      __syncthreads();                     // publish(s) before reads(s+1)
    }
  }
}

// ---------------------------------------------------------------------------
// Fallback (small ws): one launch per step.
// ---------------------------------------------------------------------------
constexpr int FT = 32;
__global__ __launch_bounds__(64) void step_kernel(
    const float* __restrict__ src, float* __restrict__ dst,
    const float* __restrict__ cv, const float* __restrict__ ch,
    const float* __restrict__ source, const float* __restrict__ mask) {
  __shared__ float sIl[FT + 2][FT + 3];
  int b = blockIdx.z;
  int ty0 = blockIdx.y * FT, tx0 = blockIdx.x * FT;
  const float* I = src + (size_t)b * Hh * Ww;
  int tid = threadIdx.x;
  for (int i = tid; i < (FT + 2) * (FT + 2); i += 64) {
    int ly = i / (FT + 2), lx = i % (FT + 2);
    int gy = max(0, min(Hh - 1, ty0 + ly - 1));
    int gx = max(0, min(Ww - 1, tx0 + lx - 1));
    sIl[ly][lx] = I[gy * Ww + gx];
  }
  __syncthreads();
  int bby = tid >> 3, bbx = tid & 7;
  int py0 = bby * 4, px0 = bbx * 4;
  int gy0 = ty0 + py0, gx0 = tx0 + px0;
  const float* cvb = cv + (size_t)b * (Hh - 1) * Ww;
  const float* chb = ch + (size_t)b * Hh * (Ww - 1);
  float v[4][4]; float sum = 0.0f;
#pragma unroll
  for (int dy = 0; dy < 4; ++dy) {
    int y = gy0 + dy, ly = py0 + dy + 1;
#pragma unroll
    for (int dx = 0; dx < 4; ++dx) {
      int x = gx0 + dx, lx = px0 + dx + 1;
      float cc = sIl[ly][lx];
      float acc = cc;
      if (y < Hh - 1) acc += Lf * cvb[y * Ww + x] * (sIl[ly + 1][lx] - cc);
      if (y > 0)      acc -= Lf * cvb[(y - 1) * Ww + x] * (cc - sIl[ly - 1][lx]);
      if (x < Ww - 1) acc += Lf * chb[y * (Ww - 1) + x] * (sIl[ly][lx + 1] - cc);
      if (x > 0)      acc -= Lf * chb[y * (Ww - 1) + x - 1] * (cc - sIl[ly][lx - 1]);
      v[dy][dx] = acc; sum += acc;
    }
  }
  int sidx = (b * SWs + (gy0 >> 2)) * SWs + (gx0 >> 2);
  float ratio = (mask[sidx] > 0.5f) ? 1.0f : source[sidx] / (sum * 0.0625f + EPSf);
  float* D = dst + (size_t)b * Hh * Ww;
#pragma unroll
  for (int dy = 0; dy < 4; ++dy)
    *reinterpret_cast<float4*>(&D[(gy0 + dy) * Ww + gx0]) =
        make_float4(v[dy][0] * ratio, v[dy][1] * ratio,
                    v[dy][2] * ratio, v[dy][3] * ratio);
}

// ---------------------------------------------------------------------------
extern "C" void kernel_launch(void* const* d_in, const int* in_sizes, int n_in,
                              void* d_out, int out_size, void* d_ws, size_t ws_size,
                              hipStream_t stream) {
  const float* guide  = (const float*)d_in[0];
  const float* ybic   = (const float*)d_in[1];
  const float* source = (const float*)d_in[2];
  const float* mask   = (const float*)d_in[3];

  float* out   = (float*)d_out;
  float* ypred = out;                 // 524288
  float* cv    = out + NPIX;          // 523264
  float* ch    = out + NPIX + CVN;    // 523264

  cvch_kernel<<<dim3((NPIX + 255) / 256), dim3(256), 0, stream>>>(ybic, guide, cv, ch);

  size_t needPing = (size_t)2 * NPIX * sizeof(float);                 // 4 MB
  size_t needCoef = (size_t)NWG * NTHR * CREC * sizeof(unsigned);     // 21 MB

  if (ws_size >= needPing + needCoef) {
    float* wsb0 = (float*)d_ws;
    float* wsb1 = wsb0 + NPIX;
    unsigned* crec = (unsigned*)(wsb1 + NPIX);
    coefpack_kernel<<<dim3(NWG), dim3(NTHR), 0, stream>>>(cv, ch, crec);
    const float* sp = ybic;
    for (int l = 0; l < NLAUNCH; ++l) {
      float* dp = (l == NLAUNCH - 1) ? ypred : ((l & 1) ? wsb1 : wsb0);
      diffuse8_kernel<<<dim3(NWG), dim3(NTHR), 0, stream>>>(sp, dp, crec,
                                                            source, mask);
      sp = dp;
    }
  } else {
    float* wsbuf = (float*)d_ws;
    dim3 grid(Ww / FT, Hh / FT, Bn);
    const float* sp = ybic;
    for (int it = 0; it < NSTEPS; ++it) {
      float* dp = (it & 1) ? ypred : wsbuf;
      step_kernel<<<grid, dim3(64), 0, stream>>>(sp, dp, cv, ch, source, mask);
      sp = dp;
    }
  }
}

// Round 16
// 306.434 us; speedup vs baseline: 1.8529x; 1.0801x over previous
//
#include <hip/hip_runtime.h>

// GADBase diffusion: B=2, H=W=512, 128 iterations of fused diffuse+adjust.
// FINAL (R13 champion + prologue cleanup): KS=5 register-resident temporal
// blocking. 256 threads own interior 16x16 4x4-blocks of a 72x72 region
// around each 32x32 output tile; per step only block edges go through LDS
// (parity-double-buffered, 1 barrier/step). Per-(tile,thread) L-folded
// coefficients precomputed once into d_ws (21 MB, L2-resident).
// 28 dispatches: cvch + coefpack + 26 diffuse (25x5 + 1x3 steps).
//
// Measured design space (rounds 1-15): per-dependent-dispatch fixed cost
// ~6-7us; grid.sync ~55us/step; global dataflow sync ~14us/step; KS=4 -> 454,
// KS=5 -> 306, KS=7/8 -> 330-570 (occupancy/register/L2 pressure). KS=5 at
// 4 waves/WG is the empirical optimum of NDISP*fixed + sum(exec).
constexpr int Hh = 512, Ww = 512, Bn = 2;
constexpr int SWs = 128;
constexpr float Lf = 0.24f;
constexpr float Kf = 0.03f;
constexpr float EPSf = 1e-8f;
constexpr int NSTEPS = 128;

constexpr int NPIX = Bn * Hh * Ww;        // 524288
constexpr int CVN  = Bn * (Hh - 1) * Ww;  // 523264

constexpr int OT = 32;                    // output tile side
constexpr int KS = 5;                     // steps per launch
constexpr int HALO = 4 * KS;              // 20
constexpr int G = (OT + 2 * HALO) / 4;    // 18x18 block grid per region
constexpr int NREC = G * G;               // 324
constexpr int REC = 20;                   // edge record stride (dwords)
constexpr int BUFSZ = NREC * REC;         // 6480 dwords per parity buffer
constexpr int NWG = Bn * (Hh / OT) * (Ww / OT);  // 512
constexpr int CREC = 40;                  // coef record: 40 dwords / thread

__device__ __forceinline__ int clampi(int v, int lo, int hi) {
  return min(max(v, lo), hi);
}
// Linear record offset. REC=20 staggers bank bases (t*20 mod 32 cycles
// {0,20,8,28,16,4,24,12}). Records use 16 of 20 dwords; NO per-record shift
// (round-7 lesson: any shift >=4 dwords collides with the next record).
__device__ __forceinline__ int recof(int t) { return t * REC; }

// ---------------------------------------------------------------------------
// Kernel 1: edge-stopping coefficients cv, ch (once, into d_out slots).
// ---------------------------------------------------------------------------
__global__ __launch_bounds__(256) void cvch_kernel(
    const float* __restrict__ img, const float* __restrict__ guide,
    float* __restrict__ cv, float* __restrict__ ch) {
  int idx = blockIdx.x * blockDim.x + threadIdx.x;
  if (idx >= NPIX) return;
  int x = idx & (Ww - 1);
  int y = (idx >> 9) & (Hh - 1);
  int b = idx >> 18;
  const float inv_k2 = 1.0f / (Kf * Kf);
  const float* f0 = img + (size_t)b * Hh * Ww;
  const float* g0 = guide + (size_t)b * 3 * Hh * Ww;
  const float* g1 = g0 + Hh * Ww;
  const float* g2 = g1 + Hh * Ww;
  int p = y * Ww + x;
  float c0 = f0[p], c1 = g0[p], c2 = g1[p], c3 = g2[p];
  if (y < Hh - 1) {
    int q = p + Ww;
    float m = (fabsf(f0[q] - c0) + fabsf(g0[q] - c1) +
               fabsf(g1[q] - c2) + fabsf(g2[q] - c3)) * 0.25f;
    cv[(b * (Hh - 1) + y) * Ww + x] = 1.0f / (1.0f + m * m * inv_k2);
  }
  if (x < Ww - 1) {
    int q = p + 1;
    float m = (fabsf(f0[q] - c0) + fabsf(g0[q] - c1) +
               fabsf(g1[q] - c2) + fabsf(g2[q] - c3)) * 0.25f;
    ch[(b * Hh + y) * (Ww - 1) + x] = 1.0f / (1.0f + m * m * inv_k2);
  }
}

// ---------------------------------------------------------------------------
// Kernel 1b: pack per-(tile,thread) L-folded coefficients into d_ws records.
// Record (CREC=40 dwords): cvk[5][4] at +0..19, chk[4][5] at +20..39.
// Thread mapping EXACTLY matches diffuse5_kernel.
// ---------------------------------------------------------------------------
__global__ __launch_bounds__(256) void coefpack_kernel(
    const float* __restrict__ cv, const float* __restrict__ ch,
    float* __restrict__ crec) {
  int wg = blockIdx.x;
  int b  = wg >> 8;
  int t  = wg & 255;
  int Ty0 = (t >> 4) * OT;
  int Tx0 = (t & 15) * OT;
  int tid = threadIdx.x;
  int by = 1 + (tid >> 4), bx = 1 + (tid & 15);
  int gy0 = Ty0 - HALO + 4 * by;
  int gx0 = Tx0 - HALO + 4 * bx;

  const float* cvb = cv + (size_t)b * (Hh - 1) * Ww;
  const float* chb = ch + (size_t)b * Hh * (Ww - 1);
  float* r = crec + ((size_t)wg * 256 + tid) * CREC;

#pragma unroll
  for (int k = 0; k < 5; ++k) {
    int ro = gy0 - 1 + k;
    float4 o;
    if (ro < 0 || ro > Hh - 2) {
      o = make_float4(0.f, 0.f, 0.f, 0.f);
    } else if (gx0 < 0) {
      float v = Lf * cvb[ro * Ww];
      o = make_float4(v, v, v, v);
    } else if (gx0 > Ww - 4) {
      float v = Lf * cvb[ro * Ww + Ww - 1];
      o = make_float4(v, v, v, v);
    } else {
      float4 t4 = *reinterpret_cast<const float4*>(&cvb[ro * Ww + gx0]);
      o = make_float4(Lf * t4.x, Lf * t4.y, Lf * t4.z, Lf * t4.w);
    }
    *reinterpret_cast<float4*>(r + 4 * k) = o;
  }
#pragma unroll
  for (int rr = 0; rr < 4; ++rr) {
    int ri = clampi(gy0 + rr, 0, Hh - 1);
#pragma unroll
    for (int j = 0; j < 5; ++j) {
      int e = gx0 - 1 + j;
      r[20 + rr * 5 + j] =
          (e >= 0 && e <= Ww - 2) ? Lf * chb[ri * (Ww - 1) + e] : 0.0f;
    }
  }
}

// ---------------------------------------------------------------------------
// Kernel 2: up to 5 diffusion+adjust steps per launch, block state in regs.
// 256 threads = interior 16x16 blocks of an 18x18 block grid (72x72 region
// around a 32x32 output tile). Coefficients: 10 streaming float4 loads from
// the precomputed record. Parity-double-buffered LDS edge records -> one
// barrier per step (write buf[s&1] -> sync -> read; consecutive steps target
// opposite buffers, so no WAR hazard). Shrinking active set: step s computes
// blocks [s+1, 17-s)^2; publish gate (s, G-1-s) covers step-s+1 readers
// exactly; final central 8x8 blocks = the 32x32 output tile. Off-image
// pixels are decoupled (boundary-crossing coefficients exactly 0).
// ---------------------------------------------------------------------------
__global__ __launch_bounds__(256, 3) void diffuse5_kernel(
    const float* __restrict__ src, float* __restrict__ dst,
    const float* __restrict__ crec,
    const float* __restrict__ source, const float* __restrict__ mask,
    int nsteps) {
  __shared__ __align__(16) float ebuf[2 * BUFSZ];  // 51.8 KB (2 parity bufs)

  int wg = blockIdx.x;
  int b  = wg >> 8;                        // 256 tiles per image
  int t  = wg & 255;
  int Ty0 = (t >> 4) * OT;
  int Tx0 = (t & 15) * OT;

  int tid = threadIdx.x;
  int by = 1 + (tid >> 4), bx = 1 + (tid & 15);
  int gy0 = Ty0 - HALO + 4 * by;           // block origin (may be off-image)
  int gx0 = Tx0 - HALO + 4 * bx;

  // step-invariant record offsets (dwords) within a parity buffer
  int blk = by * G + bx;
  int oMy = recof(blk);
  int oU  = recof(blk - G) + 4;            // upper neighbor's bottom row
  int oD  = recof(blk + G) + 0;            // lower neighbor's top row
  int oL  = recof(blk - 1) + 12;           // left neighbor's right col
  int oR  = recof(blk + 1) + 8;            // right neighbor's left col

  const size_t ib = (size_t)b * Hh * Ww;
  const float* S = src + ib;
  float* D = dst + ib;

  auto ld4 = [&](int gy, int gx) -> float4 {
    gy = clampi(gy, 0, Hh - 1);
    if (gx < 0)      { float v = S[gy * Ww];          return make_float4(v, v, v, v); }
    if (gx > Ww - 4) { float v = S[gy * Ww + Ww - 1]; return make_float4(v, v, v, v); }
    return *reinterpret_cast<const float4*>(&S[gy * Ww + gx]);
  };

  // --- streaming coefficient load: 10 contiguous float4s (L2-resident) ---
  float cvk[5][4];
  float chk[4][5];
  {
    const float* r = crec + ((size_t)wg * 256 + tid) * CREC;
    float cf[40];
#pragma unroll
    for (int q = 0; q < 10; ++q) {
      float4 t4 = *reinterpret_cast<const float4*>(r + 4 * q);
      cf[4 * q + 0] = t4.x; cf[4 * q + 1] = t4.y;
      cf[4 * q + 2] = t4.z; cf[4 * q + 3] = t4.w;
    }
#pragma unroll
    for (int k = 0; k < 5; ++k)
#pragma unroll
      for (int c = 0; c < 4; ++c) cvk[k][c] = cf[k * 4 + c];
#pragma unroll
    for (int rr = 0; rr < 4; ++rr)
#pragma unroll
      for (int j = 0; j < 5; ++j) chk[rr][j] = cf[20 + rr * 5 + j];
  }

  // --- own 4x4 block + initial neighbor edges (time 0, from global) ------
  float I[4][4];
#pragma unroll
  for (int r = 0; r < 4; ++r) {
    float4 t4 = ld4(gy0 + r, gx0);
    I[r][0] = t4.x; I[r][1] = t4.y; I[r][2] = t4.z; I[r][3] = t4.w;
  }
  float nT[4], nB[4], nL[4], nR[4];
  {
    float4 t4 = ld4(gy0 - 1, gx0);
    nT[0] = t4.x; nT[1] = t4.y; nT[2] = t4.z; nT[3] = t4.w;
    t4 = ld4(gy0 + 4, gx0);
    nB[0] = t4.x; nB[1] = t4.y; nB[2] = t4.z; nB[3] = t4.w;
    int cL = clampi(gx0 - 1, 0, Ww - 1), cR = clampi(gx0 + 4, 0, Ww - 1);
#pragma unroll
    for (int r = 0; r < 4; ++r) {
      int gy = clampi(gy0 + r, 0, Hh - 1);
      nL[r] = S[gy * Ww + cL];
      nR[r] = S[gy * Ww + cR];
    }
  }

  int sy = clampi(gy0 >> 2, 0, SWs - 1);
  int sx = clampi(gx0 >> 2, 0, SWs - 1);
  int sidx = (b * SWs + sy) * SWs + sx;
  float srcv = source[sidx];
  bool mskv = mask[sidx] > 0.5f;

#pragma unroll
  for (int s = 0; s < KS; ++s) {
    if (s >= nsteps) break;                // uniform; outside barrier region
    if (s > 0) {
      // read neighbor edges published at step s-1 (parity (s-1)&1)
      const float* eb = ebuf + ((s - 1) & 1) * BUFSZ;
      float4 t4;
      t4 = *reinterpret_cast<const float4*>(eb + oU);
      nT[0] = t4.x; nT[1] = t4.y; nT[2] = t4.z; nT[3] = t4.w;
      t4 = *reinterpret_cast<const float4*>(eb + oD);
      nB[0] = t4.x; nB[1] = t4.y; nB[2] = t4.z; nB[3] = t4.w;
      t4 = *reinterpret_cast<const float4*>(eb + oL);
      nL[0] = t4.x; nL[1] = t4.y; nL[2] = t4.z; nL[3] = t4.w;
      t4 = *reinterpret_cast<const float4*>(eb + oR);
      nR[0] = t4.x; nR[1] = t4.y; nR[2] = t4.z; nR[3] = t4.w;
    }

    float V[4][4];
    float sum = 0.0f;
#pragma unroll
    for (int r = 0; r < 4; ++r)
#pragma unroll
      for (int c = 0; c < 4; ++c) {
        float cc = I[r][c];
        float up = (r == 0) ? nT[c] : I[r - 1][c];
        float dn = (r == 3) ? nB[c] : I[r + 1][c];
        float lf = (c == 0) ? nL[r] : I[r][c - 1];
        float rt = (c == 3) ? nR[r] : I[r][c + 1];
        float acc = cc + cvk[r + 1][c] * (dn - cc) - cvk[r][c] * (cc - up)
                       + chk[r][c + 1] * (rt - cc) - chk[r][c] * (cc - lf);
        V[r][c] = acc;
        sum += acc;
      }
    float ratio = mskv ? 1.0f : __fdividef(srcv, sum * 0.0625f + EPSf);
#pragma unroll
    for (int r = 0; r < 4; ++r)
#pragma unroll
      for (int c = 0; c < 4; ++c) I[r][c] = V[r][c] * ratio;

    if (s == nsteps - 1) {
      // final values -> global (central 8x8 blocks == the 32x32 output tile)
      if (by >= 5 && by < 13 && bx >= 5 && bx < 13) {
#pragma unroll
        for (int r = 0; r < 4; ++r)
          *reinterpret_cast<float4*>(&D[(gy0 + r) * Ww + gx0]) =
              make_float4(I[r][0], I[r][1], I[r][2], I[r][3]);
      }
    } else {
      // publish edges to parity buffer s&1, then ONE barrier
      float* eb = ebuf + (s & 1) * BUFSZ;
      if (by > s && by < G - 1 - s && bx > s && bx < G - 1 - s) {
        *reinterpret_cast<float4*>(eb + oMy + 0) =
            make_float4(I[0][0], I[0][1], I[0][2], I[0][3]);   // top row
        *reinterpret_cast<float4*>(eb + oMy + 4) =
            make_float4(I[3][0], I[3][1], I[3][2], I[3][3]);   // bottom row
        *reinterpret_cast<float4*>(eb + oMy + 8) =
            make_float4(I[0][0], I[1][0], I[2][0], I[3][0]);   // left col
        *reinterpret_cast<float4*>(eb + oMy + 12) =
            make_float4(I[0][3], I[1][3], I[2][3], I[3][3]);   // right col
      }
      __syncthreads();
    }
  }
}

// ---------------------------------------------------------------------------
// Fallback (small ws): one launch per step.
// ---------------------------------------------------------------------------
constexpr int FT = 32;
__global__ __launch_bounds__(64) void step_kernel(
    const float* __restrict__ src, float* __restrict__ dst,
    const float* __restrict__ cv, const float* __restrict__ ch,
    const float* __restrict__ source, const float* __restrict__ mask) {
  __shared__ float sIl[FT + 2][FT + 3];
  int b = blockIdx.z;
  int ty0 = blockIdx.y * FT, tx0 = blockIdx.x * FT;
  const float* I = src + (size_t)b * Hh * Ww;
  int tid = threadIdx.x;
  for (int i = tid; i < (FT + 2) * (FT + 2); i += 64) {
    int ly = i / (FT + 2), lx = i % (FT + 2);
    int gy = max(0, min(Hh - 1, ty0 + ly - 1));
    int gx = max(0, min(Ww - 1, tx0 + lx - 1));
    sIl[ly][lx] = I[gy * Ww + gx];
  }
  __syncthreads();
  int bby = tid >> 3, bbx = tid & 7;
  int py0 = bby * 4, px0 = bbx * 4;
  int gy0 = ty0 + py0, gx0 = tx0 + px0;
  const float* cvb = cv + (size_t)b * (Hh - 1) * Ww;
  const float* chb = ch + (size_t)b * Hh * (Ww - 1);
  float v[4][4]; float sum = 0.0f;
#pragma unroll
  for (int dy = 0; dy < 4; ++dy) {
    int y = gy0 + dy, ly = py0 + dy + 1;
#pragma unroll
    for (int dx = 0; dx < 4; ++dx) {
      int x = gx0 + dx, lx = px0 + dx + 1;
      float cc = sIl[ly][lx];
      float acc = cc;
      if (y < Hh - 1) acc += Lf * cvb[y * Ww + x] * (sIl[ly + 1][lx] - cc);
      if (y > 0)      acc -= Lf * cvb[(y - 1) * Ww + x] * (cc - sIl[ly - 1][lx]);
      if (x < Ww - 1) acc += Lf * chb[y * (Ww - 1) + x] * (sIl[ly][lx + 1] - cc);
      if (x > 0)      acc -= Lf * chb[y * (Ww - 1) + x - 1] * (cc - sIl[ly][lx - 1]);
      v[dy][dx] = acc; sum += acc;
    }
  }
  int sidx = (b * SWs + (gy0 >> 2)) * SWs + (gx0 >> 2);
  float ratio = (mask[sidx] > 0.5f) ? 1.0f : source[sidx] / (sum * 0.0625f + EPSf);
  float* D = dst + (size_t)b * Hh * Ww;
#pragma unroll
  for (int dy = 0; dy < 4; ++dy)
    *reinterpret_cast<float4*>(&D[(gy0 + dy) * Ww + gx0]) =
        make_float4(v[dy][0] * ratio, v[dy][1] * ratio,
                    v[dy][2] * ratio, v[dy][3] * ratio);
}

// ---------------------------------------------------------------------------
extern "C" void kernel_launch(void* const* d_in, const int* in_sizes, int n_in,
                              void* d_out, int out_size, void* d_ws, size_t ws_size,
                              hipStream_t stream) {
  const float* guide  = (const float*)d_in[0];
  const float* ybic   = (const float*)d_in[1];
  const float* source = (const float*)d_in[2];
  const float* mask   = (const float*)d_in[3];

  float* out   = (float*)d_out;
  float* ypred = out;                 // 524288
  float* cv    = out + NPIX;          // 523264
  float* ch    = out + NPIX + CVN;    // 523264

  cvch_kernel<<<dim3((NPIX + 255) / 256), dim3(256), 0, stream>>>(ybic, guide, cv, ch);

  size_t needPing = (size_t)2 * NPIX * sizeof(float);                // 4 MB
  size_t needCoef = (size_t)NWG * 256 * CREC * sizeof(float);        // 21 MB

  if (ws_size >= needPing + needCoef) {
    float* wsb0 = (float*)d_ws;
    float* wsb1 = wsb0 + NPIX;
    float* crec = wsb1 + NPIX;
    coefpack_kernel<<<dim3(NWG), dim3(256), 0, stream>>>(cv, ch, crec);
    const float* sp = ybic;
    int done = 0, l = 0;
    while (done < NSTEPS) {
      int ns = (NSTEPS - done >= KS) ? KS : (NSTEPS - done);   // 25x5 + 1x3
      bool lastL = (done + ns == NSTEPS);
      float* dp = lastL ? ypred : ((l & 1) ? wsb1 : wsb0);
      diffuse5_kernel<<<dim3(NWG), dim3(256), 0, stream>>>(sp, dp, crec,
                                                           source, mask, ns);
      sp = dp; done += ns; ++l;
    }
  } else {
    float* wsbuf = (float*)d_ws;
    dim3 grid(Ww / FT, Hh / FT, Bn);
    const float* sp = ybic;
    for (int it = 0; it < NSTEPS; ++it) {
      float* dp = (it & 1) ? ypred : wsbuf;
      step_kernel<<<grid, dim3(64), 0, stream>>>(sp, dp, cv, ch, source, mask);
      sp = dp;
    }
  }
}